// Round 1
// baseline (264.068 us; speedup 1.0000x reference)
//
#include <hip/hip_runtime.h>
#include <stdint.h>

typedef uint32_t u32;
typedef __attribute__((ext_vector_type(4))) float f32x4;
typedef __attribute__((ext_vector_type(8))) short short8;

#define NBATCH 16
#define NPIX   16384      // H*W
#define NPB    1048576    // per-batch flat elems (C*H*W = 1024*1024)

__device__ __forceinline__ ushort f2bf(float f) {
  u32 b = __builtin_bit_cast(u32, f);
  return (ushort)((b + 0x7FFFu + ((b >> 16) & 1u)) >> 16);
}
__device__ __forceinline__ float bf2f(ushort h) {
  return __builtin_bit_cast(float, (u32)h << 16);
}

// ---------------- Kernel 1: projections --------------------------------------
// 80 outputs per pixel: [0..7]=q, [8..15]=k, [16..79]=v. Block = 5 waves x 64
// lanes, 256 consecutive pixels (4/lane). Wave w owns outputs [16w, 16w+16).
__global__ __launch_bounds__(320) void proj_kernel(
    const float* __restrict__ x,
    const float* __restrict__ Wq, const float* __restrict__ bq,
    const float* __restrict__ Wk, const float* __restrict__ bk,
    const float* __restrict__ Wv, const float* __restrict__ bv,
    ushort* __restrict__ Qt2, ushort* __restrict__ Kt2,
    ushort* __restrict__ Vnat)
{
  __shared__ float wlds[80 * 64];
  __shared__ float blds[80];
  int t = threadIdx.x;
  for (int i = t; i < 80 * 64; i += 320) {
    int r = i >> 6, c = i & 63;
    float v;
    if (r < 8)       v = Wq[r * 64 + c];
    else if (r < 16) v = Wk[(r - 8) * 64 + c];
    else             v = Wv[(r - 16) * 64 + c];
    wlds[i] = v;
  }
  if (t < 80) blds[t] = (t < 8) ? bq[t] : (t < 16 ? bk[t - 8] : bv[t - 16]);
  __syncthreads();

  int blk = blockIdx.x;
  int b = blk >> 6;
  int p0 = (blk & 63) << 8;
  int wave = t >> 6, lane = t & 63;
  int p = p0 + lane * 4;
  int obase = wave * 16;

  const float* xb = x + (size_t)b * NPB;
  const f32x4* wlds4 = (const f32x4*)wlds;

  float acc[16][4];
  #pragma unroll
  for (int o = 0; o < 16; ++o) {
    float bb = blds[obase + o];
    acc[o][0] = bb; acc[o][1] = bb; acc[o][2] = bb; acc[o][3] = bb;
  }

  for (int cb = 0; cb < 16; ++cb) {
    f32x4 xv0 = *(const f32x4*)(xb + (size_t)(cb * 4 + 0) * NPIX + p);
    f32x4 xv1 = *(const f32x4*)(xb + (size_t)(cb * 4 + 1) * NPIX + p);
    f32x4 xv2 = *(const f32x4*)(xb + (size_t)(cb * 4 + 2) * NPIX + p);
    f32x4 xv3 = *(const f32x4*)(xb + (size_t)(cb * 4 + 3) * NPIX + p);
    #pragma unroll
    for (int o = 0; o < 16; ++o) {
      f32x4 w = wlds4[(obase + o) * 16 + cb];
      #pragma unroll
      for (int i = 0; i < 4; ++i)
        acc[o][i] += w[0] * xv0[i] + w[1] * xv1[i] + w[2] * xv2[i] + w[3] * xv3[i];
    }
  }

  if (wave == 0) {
    int tc = p0 >> 10;  // constant within block (256-aligned tile)
    #pragma unroll
    for (int o = 0; o < 8; ++o) {
      #pragma unroll
      for (int i = 0; i < 4; ++i) {
        int pp = p + i;
        int l = pp & 1023;
        int m = o * 16 + tc;
        float qv = acc[o][i];
        ushort qh = f2bf(qv);
        ushort ql = f2bf(qv - bf2f(qh));
        ushort* qrow = Qt2 + ((size_t)b * 1024 + l) * 384;
        qrow[m] = qh; qrow[128 + m] = ql; qrow[256 + m] = qh;
        float kv = acc[8 + o][i];
        ushort kh = f2bf(kv);
        ushort kl = f2bf(kv - bf2f(kh));
        ushort* krow = Kt2 + ((size_t)b * 1024 + l) * 384;
        krow[m] = kh; krow[128 + m] = kh; krow[256 + m] = kl;
      }
    }
  } else {
    int ov = obase - 16;
    #pragma unroll
    for (int o = 0; o < 16; ++o) {
      union { ushort s[4]; uint2 q; } pk;
      #pragma unroll
      for (int i = 0; i < 4; ++i) pk.s[i] = f2bf(acc[o][i]);
      *reinterpret_cast<uint2*>(Vnat + ((size_t)b * 64 + ov + o) * NPIX + p) = pk.q;
    }
  }
}

// ---------------- Kernel 2: V transpose --------------------------------------
// Vt[b][c][p] = Vnat[b][p>>4][(p&15)*1024 + c]; 64x64 tiles via LDS.
__global__ __launch_bounds__(256) void transpose_v(
    const ushort* __restrict__ Vnat, ushort* __restrict__ Vt)
{
  __shared__ ushort tile[64][80];
  int b = blockIdx.y;
  int p0 = (blockIdx.x >> 4) << 6;
  int c0 = (blockIdx.x & 15) << 6;
  int t = threadIdx.x;
  int pr = t >> 2, ch = t & 3;
  int p = p0 + pr;
  const ushort* src = Vnat + (size_t)b * NPB + (size_t)(p >> 4) * NPIX +
                      (size_t)(p & 15) * 1024 + c0 + ch * 16;
  uint4 v0 = ((const uint4*)src)[0];
  uint4 v1 = ((const uint4*)src)[1];
  *(uint4*)&tile[pr][ch * 16] = v0;
  *(uint4*)&tile[pr][ch * 16 + 8] = v1;
  __syncthreads();
  int cl = t >> 2, pch = t & 3;
  union { ushort s[16]; uint4 q[2]; } outv;
  #pragma unroll
  for (int j = 0; j < 16; ++j) outv.s[j] = tile[pch * 16 + j][cl];
  ushort* dst = Vt + (size_t)b * NPB + (size_t)(c0 + cl) * 1024 + p0 + pch * 16;
  ((uint4*)dst)[0] = outv.q[0];
  ((uint4*)dst)[1] = outv.q[1];
}

// ---------------- Kernels 3/5: NT bf16 MFMA GEMM -----------------------------
// C[i][j] = sum_k A[i][k]*B[j][k]; per-batch 1024x1024, tile 128x128, BK=64.
// 4 waves (2x2), each 64x64 via 4x4 frags of 16x16x32. XOR-swizzled LDS.
template<int KTOT, bool ADDX>
__global__ __launch_bounds__(256) void gemm_nt(
    const ushort* __restrict__ A, int lda,
    const ushort* __restrict__ B, int ldb,
    float* __restrict__ C, const float* __restrict__ X)
{
  __shared__ ushort Asm[128 * 64];
  __shared__ ushort Bsm[128 * 64];
  int t = threadIdx.x;
  int bz = blockIdx.z;
  int m0 = blockIdx.y << 7, n0 = blockIdx.x << 7;
  const ushort* Ab = A + (size_t)bz * 1024 * lda;
  const ushort* Bb = B + (size_t)bz * 1024 * ldb;
  int row = t >> 1, half = t & 1;
  int swz = row & 7;
  int wid = t >> 6, lane = t & 63;
  int wm = wid >> 1, wn = wid & 1;

  f32x4 acc[4][4] = {};
  uint4* as4 = (uint4*)Asm;
  uint4* bs4 = (uint4*)Bsm;
  const uint4* agrow = (const uint4*)(Ab + (size_t)(m0 + row) * lda) + half * 4;
  const uint4* bgrow = (const uint4*)(Bb + (size_t)(n0 + row) * ldb) + half * 4;

  for (int k0 = 0; k0 < KTOT; k0 += 64) {
    uint4 a0 = agrow[0], a1 = agrow[1], a2 = agrow[2], a3 = agrow[3];
    uint4 b0 = bgrow[0], b1 = bgrow[1], b2 = bgrow[2], b3 = bgrow[3];
    agrow += 8; bgrow += 8;
    __syncthreads();
    int sb = row * 8, c0i = half * 4;
    as4[sb + ((c0i + 0) ^ swz)] = a0;
    as4[sb + ((c0i + 1) ^ swz)] = a1;
    as4[sb + ((c0i + 2) ^ swz)] = a2;
    as4[sb + ((c0i + 3) ^ swz)] = a3;
    bs4[sb + ((c0i + 0) ^ swz)] = b0;
    bs4[sb + ((c0i + 1) ^ swz)] = b1;
    bs4[sb + ((c0i + 2) ^ swz)] = b2;
    bs4[sb + ((c0i + 3) ^ swz)] = b3;
    __syncthreads();
    #pragma unroll
    for (int kk = 0; kk < 2; ++kk) {
      short8 af[4], bfr[4];
      #pragma unroll
      for (int mi = 0; mi < 4; ++mi) {
        int r = (wm << 6) + (mi << 4) + (lane & 15);
        af[mi] = __builtin_bit_cast(short8,
            ((const uint4*)Asm)[r * 8 + ((kk * 4 + (lane >> 4)) ^ (r & 7))]);
      }
      #pragma unroll
      for (int ni = 0; ni < 4; ++ni) {
        int r = (wn << 6) + (ni << 4) + (lane & 15);
        bfr[ni] = __builtin_bit_cast(short8,
            ((const uint4*)Bsm)[r * 8 + ((kk * 4 + (lane >> 4)) ^ (r & 7))]);
      }
      #pragma unroll
      for (int mi = 0; mi < 4; ++mi)
        #pragma unroll
        for (int ni = 0; ni < 4; ++ni)
          acc[mi][ni] = __builtin_amdgcn_mfma_f32_16x16x32_bf16(
              af[mi], bfr[ni], acc[mi][ni], 0, 0, 0);
    }
  }

  #pragma unroll
  for (int mi = 0; mi < 4; ++mi) {
    int rbase = m0 + (wm << 6) + (mi << 4) + ((lane >> 4) << 2);
    #pragma unroll
    for (int ni = 0; ni < 4; ++ni) {
      int col = n0 + (wn << 6) + (ni << 4) + (lane & 15);
      f32x4 v = acc[mi][ni];
      #pragma unroll
      for (int r = 0; r < 4; ++r) {
        size_t idx = ((size_t)bz * 1024 + rbase + r) * 1024 + col;
        if (ADDX) C[idx] = v[r] + X[idx];
        else      C[idx] = v[r];
      }
    }
  }
}

// ---------------- Kernel 4: row softmax, P bf16 in place ---------------------
__global__ __launch_bounds__(256) void softmax_rows(float* __restrict__ S)
{
  size_t rowi = blockIdx.x;
  float* srow = S + rowi * 1024;
  int t = threadIdx.x;
  float4 v = ((const float4*)srow)[t];
  float m = fmaxf(fmaxf(v.x, v.y), fmaxf(v.z, v.w));
  #pragma unroll
  for (int off = 32; off > 0; off >>= 1) m = fmaxf(m, __shfl_xor(m, off));
  __shared__ float red[8];
  int wid = t >> 6, lane = t & 63;
  if (lane == 0) red[wid] = m;
  __syncthreads();
  m = fmaxf(fmaxf(red[0], red[1]), fmaxf(red[2], red[3]));
  float e0 = __expf(v.x - m), e1 = __expf(v.y - m);
  float e2 = __expf(v.z - m), e3 = __expf(v.w - m);
  float s = e0 + e1 + e2 + e3;
  #pragma unroll
  for (int off = 32; off > 0; off >>= 1) s += __shfl_xor(s, off);
  if (lane == 0) red[4 + wid] = s;
  __syncthreads();
  s = red[4] + red[5] + red[6] + red[7];
  float inv = 1.0f / s;
  union { ushort h[4]; uint2 q; } pk;
  pk.h[0] = f2bf(e0 * inv); pk.h[1] = f2bf(e1 * inv);
  pk.h[2] = f2bf(e2 * inv); pk.h[3] = f2bf(e3 * inv);
  ((uint2*)srow)[t] = pk.q;
}

// ---------------- Launch -----------------------------------------------------
extern "C" void kernel_launch(void* const* d_in, const int* in_sizes, int n_in,
                              void* d_out, int out_size, void* d_ws, size_t ws_size,
                              hipStream_t stream) {
  const float* x  = (const float*)d_in[0];
  const float* Wq = (const float*)d_in[1];
  const float* bq = (const float*)d_in[2];
  const float* Wk = (const float*)d_in[3];
  const float* bk = (const float*)d_in[4];
  const float* Wv = (const float*)d_in[5];
  const float* bv = (const float*)d_in[6];
  float* out = (float*)d_out;

  char* wsb = (char*)d_ws;
  ushort* Qt2 = (ushort*)wsb;                          // 12,582,912 B
  ushort* Kt2 = (ushort*)(wsb + 12582912);             // 12,582,912 B
  ushort* Vt  = (ushort*)(wsb + 25165824);             // 33,554,432 B
  float*  S   = (float*)(wsb + 58720256);              // 67,108,864 B (P in place)
  ushort* Vnat = (ushort*)S;                           // aliased (dead before gemm1)

  proj_kernel<<<1024, 320, 0, stream>>>(x, Wq, bq, Wk, bk, Wv, bv, Qt2, Kt2, Vnat);
  transpose_v<<<dim3(256, 16), 256, 0, stream>>>(Vnat, Vt);
  gemm_nt<384, false><<<dim3(8, 8, 16), 256, 0, stream>>>(Qt2, 384, Kt2, 384, S, nullptr);
  softmax_rows<<<16384, 256, 0, stream>>>(S);
  gemm_nt<1024, true><<<dim3(8, 8, 16), 256, 0, stream>>>((const ushort*)S, 2048, Vt, 1024, out, x);
}

// Round 3
// 233.986 us; speedup vs baseline: 1.1286x; 1.1286x over previous
//
#include <hip/hip_runtime.h>
#include <stdint.h>

typedef uint32_t u32;
typedef __attribute__((ext_vector_type(4))) float f32x4;
typedef __attribute__((ext_vector_type(8))) short short8;

#define NBATCH 16
#define NPIX   16384      // H*W
#define NPB    1048576    // per-batch flat elems (C*H*W = 1024*1024)

__device__ __forceinline__ ushort f2bf(float f) {
  u32 b = __builtin_bit_cast(u32, f);
  return (ushort)((b + 0x7FFFu + ((b >> 16) & 1u)) >> 16);
}
__device__ __forceinline__ float bf2f(ushort h) {
  return __builtin_bit_cast(float, (u32)h << 16);
}

// ---------------- Kernel 0: pack weights -------------------------------------
// wp[cb][o][j] = W[o][cb*4+j], o in [0,80): 0..7=q, 8..15=k, 16..79=v.
__global__ void prep_w(const float* __restrict__ Wq, const float* __restrict__ bq,
                       const float* __restrict__ Wk, const float* __restrict__ bk,
                       const float* __restrict__ Wv, const float* __restrict__ bv,
                       float* __restrict__ wp, float* __restrict__ bpk)
{
  int gid = blockIdx.x * 256 + threadIdx.x;
  if (gid < 5120) {
    int cb = gid / 320;
    int r = gid - cb * 320;
    int o = r >> 2, j = r & 3;
    int c = cb * 4 + j;
    float v = (o < 8) ? Wq[o * 64 + c]
            : (o < 16) ? Wk[(o - 8) * 64 + c]
                       : Wv[(o - 16) * 64 + c];
    wp[gid] = v;
  } else if (gid < 5200) {
    int o = gid - 5120;
    bpk[o] = (o < 8) ? bq[o] : (o < 16 ? bk[o - 8] : bv[o - 16]);
  }
}

// ---------------- Kernel 1: projections (thread-per-pixel) -------------------
// 256 threads = 256 consecutive pixels. Each thread computes all 80 outputs.
// x loads: coalesced dword loads, zero redundancy. Weights: uniform scalar
// loads from wp. Q/K stored split-bf16 with k-label m' = tc*8 + o (consistent
// bijection on both operands) so 8 outputs pack into one 16B store per region.
// V stored in NATURAL layout Vnat[b][c][pix] (coalesced); transpose_v then
// produces Vt[j][k] = v_flat[k*1024 + j] as gemm2's B operand requires.
__global__ __launch_bounds__(256) void proj2(
    const float* __restrict__ x, const float* __restrict__ wp,
    const float* __restrict__ bpk,
    ushort* __restrict__ Qt2, ushort* __restrict__ Kt2,
    ushort* __restrict__ Vnat)
{
  int t = threadIdx.x;
  int b = blockIdx.x >> 6;
  int p = ((blockIdx.x & 63) << 8) + t;
  int l = p & 1023, tc = p >> 10;
  const float* xb = x + (size_t)b * NPB + p;

  float acc[80];
  #pragma unroll
  for (int o = 0; o < 80; ++o) acc[o] = bpk[o];

  const f32x4* wp4 = (const f32x4*)wp;
  for (int cb = 0; cb < 16; ++cb) {
    float x0 = xb[(size_t)(cb * 4 + 0) << 14];
    float x1 = xb[(size_t)(cb * 4 + 1) << 14];
    float x2 = xb[(size_t)(cb * 4 + 2) << 14];
    float x3 = xb[(size_t)(cb * 4 + 3) << 14];
    #pragma unroll
    for (int o = 0; o < 80; ++o) {
      f32x4 w = wp4[cb * 80 + o];
      acc[o] += w[0] * x0 + w[1] * x1 + w[2] * x2 + w[3] * x3;
    }
  }

  // Q/K split bf16: Q = [qh][ql][qh], K = [kh][kh][kl] so that
  // dot = qh*kh + ql*kh + qh*kl (drops only ~2e-4 ql*kl term).
  union { ushort s[8]; uint4 q; } qh, ql, kh, kl;
  #pragma unroll
  for (int o = 0; o < 8; ++o) {
    float qv = acc[o];
    ushort h = f2bf(qv);
    qh.s[o] = h; ql.s[o] = f2bf(qv - bf2f(h));
    float kv = acc[8 + o];
    h = f2bf(kv);
    kh.s[o] = h; kl.s[o] = f2bf(kv - bf2f(h));
  }
  ushort* qrow = Qt2 + ((size_t)b * 1024 + l) * 384 + tc * 8;
  *(uint4*)qrow         = qh.q;
  *(uint4*)(qrow + 128) = ql.q;
  *(uint4*)(qrow + 256) = qh.q;
  ushort* krow = Kt2 + ((size_t)b * 1024 + l) * 384 + tc * 8;
  *(uint4*)krow         = kh.q;
  *(uint4*)(krow + 128) = kh.q;
  *(uint4*)(krow + 256) = kl.q;

  // V natural layout: Vnat[b][c][pix], lanes contiguous in pix -> 128B/inst.
  ushort* vb = Vnat + (size_t)b * NPB + p;
  #pragma unroll
  for (int c = 0; c < 64; ++c)
    vb[(size_t)c * 16384] = f2bf(acc[16 + c]);
}

// ---------------- Kernel 2: V transpose --------------------------------------
// Vt[a][p'] = Vnat_flat[p'*1024 + a]  (verified correct in round 1)
__global__ __launch_bounds__(256) void transpose_v(
    const ushort* __restrict__ Vnat, ushort* __restrict__ Vt)
{
  __shared__ ushort tile[64][80];
  int b = blockIdx.y;
  int p0 = (blockIdx.x >> 4) << 6;
  int c0 = (blockIdx.x & 15) << 6;
  int t = threadIdx.x;
  int pr = t >> 2, ch = t & 3;
  int p = p0 + pr;
  const ushort* src = Vnat + (size_t)b * NPB + (size_t)(p >> 4) * NPIX +
                      (size_t)(p & 15) * 1024 + c0 + ch * 16;
  uint4 v0 = ((const uint4*)src)[0];
  uint4 v1 = ((const uint4*)src)[1];
  *(uint4*)&tile[pr][ch * 16] = v0;
  *(uint4*)&tile[pr][ch * 16 + 8] = v1;
  __syncthreads();
  int cl = t >> 2, pch = t & 3;
  union { ushort s[16]; uint4 q[2]; } outv;
  #pragma unroll
  for (int j = 0; j < 16; ++j) outv.s[j] = tile[pch * 16 + j][cl];
  ushort* dst = Vt + (size_t)b * NPB + (size_t)(c0 + cl) * 1024 + p0 + pch * 16;
  ((uint4*)dst)[0] = outv.q[0];
  ((uint4*)dst)[1] = outv.q[1];
}

// ---------------- Kernels 3/5: NT bf16 MFMA GEMM -----------------------------
// C[i][j] = sum_k A[i][k]*B[j][k]; per-batch 1024x1024, tile 128x128, BK=64.
// 4 waves (2x2), each 64x64 via 4x4 frags of 16x16x32. XOR-swizzled LDS.
template<int KTOT, bool ADDX>
__global__ __launch_bounds__(256) void gemm_nt(
    const ushort* __restrict__ A, int lda,
    const ushort* __restrict__ B, int ldb,
    float* __restrict__ C, const float* __restrict__ X)
{
  __shared__ ushort Asm[128 * 64];
  __shared__ ushort Bsm[128 * 64];
  int t = threadIdx.x;
  int bz = blockIdx.z;
  int m0 = blockIdx.y << 7, n0 = blockIdx.x << 7;
  const ushort* Ab = A + (size_t)bz * 1024 * lda;
  const ushort* Bb = B + (size_t)bz * 1024 * ldb;
  int row = t >> 1, half = t & 1;
  int swz = row & 7;
  int wid = t >> 6, lane = t & 63;
  int wm = wid >> 1, wn = wid & 1;

  f32x4 acc[4][4] = {};
  uint4* as4 = (uint4*)Asm;
  uint4* bs4 = (uint4*)Bsm;
  const uint4* agrow = (const uint4*)(Ab + (size_t)(m0 + row) * lda) + half * 4;
  const uint4* bgrow = (const uint4*)(Bb + (size_t)(n0 + row) * ldb) + half * 4;

  for (int k0 = 0; k0 < KTOT; k0 += 64) {
    uint4 a0 = agrow[0], a1 = agrow[1], a2 = agrow[2], a3 = agrow[3];
    uint4 b0 = bgrow[0], b1 = bgrow[1], b2 = bgrow[2], b3 = bgrow[3];
    agrow += 8; bgrow += 8;
    __syncthreads();
    int sb = row * 8, c0i = half * 4;
    as4[sb + ((c0i + 0) ^ swz)] = a0;
    as4[sb + ((c0i + 1) ^ swz)] = a1;
    as4[sb + ((c0i + 2) ^ swz)] = a2;
    as4[sb + ((c0i + 3) ^ swz)] = a3;
    bs4[sb + ((c0i + 0) ^ swz)] = b0;
    bs4[sb + ((c0i + 1) ^ swz)] = b1;
    bs4[sb + ((c0i + 2) ^ swz)] = b2;
    bs4[sb + ((c0i + 3) ^ swz)] = b3;
    __syncthreads();
    #pragma unroll
    for (int kk = 0; kk < 2; ++kk) {
      short8 af[4], bfr[4];
      #pragma unroll
      for (int mi = 0; mi < 4; ++mi) {
        int r = (wm << 6) + (mi << 4) + (lane & 15);
        af[mi] = __builtin_bit_cast(short8,
            ((const uint4*)Asm)[r * 8 + ((kk * 4 + (lane >> 4)) ^ (r & 7))]);
      }
      #pragma unroll
      for (int ni = 0; ni < 4; ++ni) {
        int r = (wn << 6) + (ni << 4) + (lane & 15);
        bfr[ni] = __builtin_bit_cast(short8,
            ((const uint4*)Bsm)[r * 8 + ((kk * 4 + (lane >> 4)) ^ (r & 7))]);
      }
      #pragma unroll
      for (int mi = 0; mi < 4; ++mi)
        #pragma unroll
        for (int ni = 0; ni < 4; ++ni)
          acc[mi][ni] = __builtin_amdgcn_mfma_f32_16x16x32_bf16(
              af[mi], bfr[ni], acc[mi][ni], 0, 0, 0);
    }
  }

  #pragma unroll
  for (int mi = 0; mi < 4; ++mi) {
    int rbase = m0 + (wm << 6) + (mi << 4) + ((lane >> 4) << 2);
    #pragma unroll
    for (int ni = 0; ni < 4; ++ni) {
      int col = n0 + (wn << 6) + (ni << 4) + (lane & 15);
      f32x4 v = acc[mi][ni];
      #pragma unroll
      for (int r = 0; r < 4; ++r) {
        size_t idx = ((size_t)bz * 1024 + rbase + r) * 1024 + col;
        if (ADDX) C[idx] = v[r] + X[idx];
        else      C[idx] = v[r];
      }
    }
  }
}

// ---------------- Kernel 4: row softmax, P bf16 in place ---------------------
__global__ __launch_bounds__(256) void softmax_rows(float* __restrict__ S)
{
  size_t rowi = blockIdx.x;
  float* srow = S + rowi * 1024;
  int t = threadIdx.x;
  float4 v = ((const float4*)srow)[t];
  float m = fmaxf(fmaxf(v.x, v.y), fmaxf(v.z, v.w));
  #pragma unroll
  for (int off = 32; off > 0; off >>= 1) m = fmaxf(m, __shfl_xor(m, off));
  __shared__ float red[8];
  int wid = t >> 6, lane = t & 63;
  if (lane == 0) red[wid] = m;
  __syncthreads();
  m = fmaxf(fmaxf(red[0], red[1]), fmaxf(red[2], red[3]));
  float e0 = __expf(v.x - m), e1 = __expf(v.y - m);
  float e2 = __expf(v.z - m), e3 = __expf(v.w - m);
  float s = e0 + e1 + e2 + e3;
  #pragma unroll
  for (int off = 32; off > 0; off >>= 1) s += __shfl_xor(s, off);
  if (lane == 0) red[4 + wid] = s;
  __syncthreads();
  s = red[4] + red[5] + red[6] + red[7];
  float inv = 1.0f / s;
  union { ushort h[4]; uint2 q; } pk;
  pk.h[0] = f2bf(e0 * inv); pk.h[1] = f2bf(e1 * inv);
  pk.h[2] = f2bf(e2 * inv); pk.h[3] = f2bf(e3 * inv);
  ((uint2*)srow)[t] = pk.q;
}

// ---------------- Launch -----------------------------------------------------
extern "C" void kernel_launch(void* const* d_in, const int* in_sizes, int n_in,
                              void* d_out, int out_size, void* d_ws, size_t ws_size,
                              hipStream_t stream) {
  const float* x  = (const float*)d_in[0];
  const float* Wq = (const float*)d_in[1];
  const float* bq = (const float*)d_in[2];
  const float* Wk = (const float*)d_in[3];
  const float* bk = (const float*)d_in[4];
  const float* Wv = (const float*)d_in[5];
  const float* bv = (const float*)d_in[6];
  float* out = (float*)d_out;

  char* wsb = (char*)d_ws;
  ushort* Qt2 = (ushort*)wsb;                          // 12,582,912 B
  ushort* Kt2 = (ushort*)(wsb + 12582912);             // 12,582,912 B
  ushort* Vt  = (ushort*)(wsb + 25165824);             // 33,554,432 B
  float*  S   = (float*)(wsb + 58720256);              // 67,108,864 B (P in place)
  ushort* Vnat = (ushort*)S;                           // first 32MB of S (dead before gemm1)
  float*  wp  = (float*)(wsb + 92274688);              // after Vnat, still inside S
  float*  bpk = wp + 5120;

  prep_w<<<21, 256, 0, stream>>>(Wq, bq, Wk, bk, Wv, bv, wp, bpk);
  proj2<<<1024, 256, 0, stream>>>(x, wp, bpk, Qt2, Kt2, Vnat);
  transpose_v<<<dim3(256, 16), 256, 0, stream>>>(Vnat, Vt);
  gemm_nt<384, false><<<dim3(8, 8, 16), 256, 0, stream>>>(Qt2, 384, Kt2, 384, S, nullptr);
  softmax_rows<<<16384, 256, 0, stream>>>(S);
  gemm_nt<1024, true><<<dim3(8, 8, 16), 256, 0, stream>>>((const ushort*)S, 2048, Vt, 1024, out, x);
}

// Round 4
// 207.478 us; speedup vs baseline: 1.2728x; 1.1278x over previous
//
#include <hip/hip_runtime.h>
#include <stdint.h>

typedef uint32_t u32;
typedef __attribute__((ext_vector_type(4))) float f32x4;
typedef __attribute__((ext_vector_type(8))) short short8;

#define NBATCH 16
#define NPIX   16384      // H*W
#define NPB    1048576    // per-batch flat elems (C*H*W = 1024*1024)

__device__ __forceinline__ ushort f2bf(float f) {
  u32 b = __builtin_bit_cast(u32, f);
  return (ushort)((b + 0x7FFFu + ((b >> 16) & 1u)) >> 16);
}
__device__ __forceinline__ float bf2f(ushort h) {
  return __builtin_bit_cast(float, (u32)h << 16);
}

// ---------------- Kernel 0: pack weights -------------------------------------
// wp[cb][o][j] = W[o][cb*4+j], o in [0,80): 0..7=q, 8..15=k, 16..79=v.
__global__ void prep_w(const float* __restrict__ Wq, const float* __restrict__ bq,
                       const float* __restrict__ Wk, const float* __restrict__ bk,
                       const float* __restrict__ Wv, const float* __restrict__ bv,
                       float* __restrict__ wp, float* __restrict__ bpk)
{
  int gid = blockIdx.x * 256 + threadIdx.x;
  if (gid < 5120) {
    int cb = gid / 320;
    int r = gid - cb * 320;
    int o = r >> 2, j = r & 3;
    int c = cb * 4 + j;
    float v = (o < 8) ? Wq[o * 64 + c]
            : (o < 16) ? Wk[(o - 8) * 64 + c]
                       : Wv[(o - 16) * 64 + c];
    wp[gid] = v;
  } else if (gid < 5200) {
    int o = gid - 5120;
    bpk[o] = (o < 8) ? bq[o] : (o < 16 ? bk[o - 8] : bv[o - 16]);
  }
}

// ---------------- Kernel 1: projections, 5 groups per pixel tile -------------
// blockIdx.x = tile*5 + g. tile = 256 consecutive pixels, 256 threads (one
// pixel each). g==0: q+k (16 outs, split-bf16 stores). g==1..4: v channels
// [16(g-1), 16g) -> Vnat. 16 accumulators/thread => no strip-mining, high
// occupancy. The 5 blocks of a tile are launch-adjacent so x re-reads hit L2/L3.
__global__ __launch_bounds__(256) void proj3(
    const float* __restrict__ x, const float* __restrict__ wp,
    const float* __restrict__ bpk,
    ushort* __restrict__ Qt2, ushort* __restrict__ Kt2,
    ushort* __restrict__ Vnat)
{
  int t = threadIdx.x;
  int g = blockIdx.x % 5;
  int tile = blockIdx.x / 5;
  int b = tile >> 6;
  int p = ((tile & 63) << 8) + t;
  int l = p & 1023, tc = p >> 10;
  const float* xb = x + (size_t)b * NPB + p;
  int ob = (g == 0) ? 0 : 16 * g;   // absolute output base in wp ordering

  float acc[16];
  #pragma unroll
  for (int o = 0; o < 16; ++o) acc[o] = bpk[ob + o];

  const f32x4* wp4 = (const f32x4*)wp;
  for (int cb = 0; cb < 16; ++cb) {
    float x0 = xb[(size_t)(cb * 4 + 0) << 14];
    float x1 = xb[(size_t)(cb * 4 + 1) << 14];
    float x2 = xb[(size_t)(cb * 4 + 2) << 14];
    float x3 = xb[(size_t)(cb * 4 + 3) << 14];
    #pragma unroll
    for (int o = 0; o < 16; ++o) {
      f32x4 w = wp4[cb * 80 + ob + o];
      acc[o] += w[0] * x0 + w[1] * x1 + w[2] * x2 + w[3] * x3;
    }
  }

  if (g == 0) {
    // Q/K split bf16: Q = [qh][ql][qh], K = [kh][kh][kl] so that
    // dot = qh*kh + ql*kh + qh*kl (drops only ~2e-4 ql*kl term).
    union { ushort s[8]; uint4 q; } qh, ql, kh, kl;
    #pragma unroll
    for (int o = 0; o < 8; ++o) {
      float qv = acc[o];
      ushort h = f2bf(qv);
      qh.s[o] = h; ql.s[o] = f2bf(qv - bf2f(h));
      float kv = acc[8 + o];
      h = f2bf(kv);
      kh.s[o] = h; kl.s[o] = f2bf(kv - bf2f(h));
    }
    ushort* qrow = Qt2 + ((size_t)b * 1024 + l) * 384 + tc * 8;
    *(uint4*)qrow         = qh.q;
    *(uint4*)(qrow + 128) = ql.q;
    *(uint4*)(qrow + 256) = qh.q;
    ushort* krow = Kt2 + ((size_t)b * 1024 + l) * 384 + tc * 8;
    *(uint4*)krow         = kh.q;
    *(uint4*)(krow + 128) = kh.q;
    *(uint4*)(krow + 256) = kl.q;
  } else {
    int cbase = 16 * (g - 1);
    ushort* vb = Vnat + (size_t)b * NPB + (size_t)cbase * NPIX + p;
    #pragma unroll
    for (int c = 0; c < 16; ++c)
      vb[(size_t)c * NPIX] = f2bf(acc[c]);
  }
}

// ---------------- Kernel 2: V transpose --------------------------------------
// Vt[a][p'] = Vnat_flat[p'*1024 + a]  (verified correct in round 1)
__global__ __launch_bounds__(256) void transpose_v(
    const ushort* __restrict__ Vnat, ushort* __restrict__ Vt)
{
  __shared__ ushort tile[64][80];
  int b = blockIdx.y;
  int p0 = (blockIdx.x >> 4) << 6;
  int c0 = (blockIdx.x & 15) << 6;
  int t = threadIdx.x;
  int pr = t >> 2, ch = t & 3;
  int p = p0 + pr;
  const ushort* src = Vnat + (size_t)b * NPB + (size_t)(p >> 4) * NPIX +
                      (size_t)(p & 15) * 1024 + c0 + ch * 16;
  uint4 v0 = ((const uint4*)src)[0];
  uint4 v1 = ((const uint4*)src)[1];
  *(uint4*)&tile[pr][ch * 16] = v0;
  *(uint4*)&tile[pr][ch * 16 + 8] = v1;
  __syncthreads();
  int cl = t >> 2, pch = t & 3;
  union { ushort s[16]; uint4 q[2]; } outv;
  #pragma unroll
  for (int j = 0; j < 16; ++j) outv.s[j] = tile[pch * 16 + j][cl];
  ushort* dst = Vt + (size_t)b * NPB + (size_t)(c0 + cl) * 1024 + p0 + pch * 16;
  ((uint4*)dst)[0] = outv.q[0];
  ((uint4*)dst)[1] = outv.q[1];
}

// ---------------- Kernels 3/5: NT bf16 MFMA GEMM -----------------------------
// C[i][j] = sum_k A[i][k]*B[j][k]; per-batch 1024x1024, tile 128x128, BK=64.
// 4 waves (2x2), each 64x64 via 4x4 frags of 16x16x32. XOR-swizzled LDS.
template<int KTOT, bool ADDX>
__global__ __launch_bounds__(256) void gemm_nt(
    const ushort* __restrict__ A, int lda,
    const ushort* __restrict__ B, int ldb,
    float* __restrict__ C, const float* __restrict__ X)
{
  __shared__ ushort Asm[128 * 64];
  __shared__ ushort Bsm[128 * 64];
  int t = threadIdx.x;
  int bz = blockIdx.z;
  int m0 = blockIdx.y << 7, n0 = blockIdx.x << 7;
  const ushort* Ab = A + (size_t)bz * 1024 * lda;
  const ushort* Bb = B + (size_t)bz * 1024 * ldb;
  int row = t >> 1, half = t & 1;
  int swz = row & 7;
  int wid = t >> 6, lane = t & 63;
  int wm = wid >> 1, wn = wid & 1;

  f32x4 acc[4][4] = {};
  uint4* as4 = (uint4*)Asm;
  uint4* bs4 = (uint4*)Bsm;
  const uint4* agrow = (const uint4*)(Ab + (size_t)(m0 + row) * lda) + half * 4;
  const uint4* bgrow = (const uint4*)(Bb + (size_t)(n0 + row) * ldb) + half * 4;

  for (int k0 = 0; k0 < KTOT; k0 += 64) {
    uint4 a0 = agrow[0], a1 = agrow[1], a2 = agrow[2], a3 = agrow[3];
    uint4 b0 = bgrow[0], b1 = bgrow[1], b2 = bgrow[2], b3 = bgrow[3];
    agrow += 8; bgrow += 8;
    __syncthreads();
    int sb = row * 8, c0i = half * 4;
    as4[sb + ((c0i + 0) ^ swz)] = a0;
    as4[sb + ((c0i + 1) ^ swz)] = a1;
    as4[sb + ((c0i + 2) ^ swz)] = a2;
    as4[sb + ((c0i + 3) ^ swz)] = a3;
    bs4[sb + ((c0i + 0) ^ swz)] = b0;
    bs4[sb + ((c0i + 1) ^ swz)] = b1;
    bs4[sb + ((c0i + 2) ^ swz)] = b2;
    bs4[sb + ((c0i + 3) ^ swz)] = b3;
    __syncthreads();
    #pragma unroll
    for (int kk = 0; kk < 2; ++kk) {
      short8 af[4], bfr[4];
      #pragma unroll
      for (int mi = 0; mi < 4; ++mi) {
        int r = (wm << 6) + (mi << 4) + (lane & 15);
        af[mi] = __builtin_bit_cast(short8,
            ((const uint4*)Asm)[r * 8 + ((kk * 4 + (lane >> 4)) ^ (r & 7))]);
      }
      #pragma unroll
      for (int ni = 0; ni < 4; ++ni) {
        int r = (wn << 6) + (ni << 4) + (lane & 15);
        bfr[ni] = __builtin_bit_cast(short8,
            ((const uint4*)Bsm)[r * 8 + ((kk * 4 + (lane >> 4)) ^ (r & 7))]);
      }
      #pragma unroll
      for (int mi = 0; mi < 4; ++mi)
        #pragma unroll
        for (int ni = 0; ni < 4; ++ni)
          acc[mi][ni] = __builtin_amdgcn_mfma_f32_16x16x32_bf16(
              af[mi], bfr[ni], acc[mi][ni], 0, 0, 0);
    }
  }

  #pragma unroll
  for (int mi = 0; mi < 4; ++mi) {
    int rbase = m0 + (wm << 6) + (mi << 4) + ((lane >> 4) << 2);
    #pragma unroll
    for (int ni = 0; ni < 4; ++ni) {
      int col = n0 + (wn << 6) + (ni << 4) + (lane & 15);
      f32x4 v = acc[mi][ni];
      #pragma unroll
      for (int r = 0; r < 4; ++r) {
        size_t idx = ((size_t)bz * 1024 + rbase + r) * 1024 + col;
        if (ADDX) C[idx] = v[r] + X[idx];
        else      C[idx] = v[r];
      }
    }
  }
}

// ---------------- Kernel 4: row softmax, P bf16 in place ---------------------
__global__ __launch_bounds__(256) void softmax_rows(float* __restrict__ S)
{
  size_t rowi = blockIdx.x;
  float* srow = S + rowi * 1024;
  int t = threadIdx.x;
  float4 v = ((const float4*)srow)[t];
  float m = fmaxf(fmaxf(v.x, v.y), fmaxf(v.z, v.w));
  #pragma unroll
  for (int off = 32; off > 0; off >>= 1) m = fmaxf(m, __shfl_xor(m, off));
  __shared__ float red[8];
  int wid = t >> 6, lane = t & 63;
  if (lane == 0) red[wid] = m;
  __syncthreads();
  m = fmaxf(fmaxf(red[0], red[1]), fmaxf(red[2], red[3]));
  float e0 = __expf(v.x - m), e1 = __expf(v.y - m);
  float e2 = __expf(v.z - m), e3 = __expf(v.w - m);
  float s = e0 + e1 + e2 + e3;
  #pragma unroll
  for (int off = 32; off > 0; off >>= 1) s += __shfl_xor(s, off);
  if (lane == 0) red[4 + wid] = s;
  __syncthreads();
  s = red[4] + red[5] + red[6] + red[7];
  float inv = 1.0f / s;
  union { ushort h[4]; uint2 q; } pk;
  pk.h[0] = f2bf(e0 * inv); pk.h[1] = f2bf(e1 * inv);
  pk.h[2] = f2bf(e2 * inv); pk.h[3] = f2bf(e3 * inv);
  ((uint2*)srow)[t] = pk.q;
}

// ---------------- Launch -----------------------------------------------------
extern "C" void kernel_launch(void* const* d_in, const int* in_sizes, int n_in,
                              void* d_out, int out_size, void* d_ws, size_t ws_size,
                              hipStream_t stream) {
  const float* x  = (const float*)d_in[0];
  const float* Wq = (const float*)d_in[1];
  const float* bq = (const float*)d_in[2];
  const float* Wk = (const float*)d_in[3];
  const float* bk = (const float*)d_in[4];
  const float* Wv = (const float*)d_in[5];
  const float* bv = (const float*)d_in[6];
  float* out = (float*)d_out;

  char* wsb = (char*)d_ws;
  ushort* Qt2 = (ushort*)wsb;                          // 12,582,912 B
  ushort* Kt2 = (ushort*)(wsb + 12582912);             // 12,582,912 B
  ushort* Vt  = (ushort*)(wsb + 25165824);             // 33,554,432 B
  float*  S   = (float*)(wsb + 58720256);              // 67,108,864 B (P in place)
  ushort* Vnat = (ushort*)S;                           // first 32MB of S (dead before gemm1)
  float*  wp  = (float*)(wsb + 92274688);              // after Vnat, still inside S
  float*  bpk = wp + 5120;

  prep_w<<<21, 256, 0, stream>>>(Wq, bq, Wk, bk, Wv, bv, wp, bpk);
  proj3<<<5120, 256, 0, stream>>>(x, wp, bpk, Qt2, Kt2, Vnat);
  transpose_v<<<dim3(256, 16), 256, 0, stream>>>(Vnat, Vt);
  gemm_nt<384, false><<<dim3(8, 8, 16), 256, 0, stream>>>(Qt2, 384, Kt2, 384, S, nullptr);
  softmax_rows<<<16384, 256, 0, stream>>>(S);
  gemm_nt<1024, true><<<dim3(8, 8, 16), 256, 0, stream>>>((const ushort*)S, 2048, Vt, 1024, out, x);
}

// Round 5
// 184.285 us; speedup vs baseline: 1.4329x; 1.1259x over previous
//
#include <hip/hip_runtime.h>
#include <stdint.h>

typedef uint32_t u32;
typedef __attribute__((ext_vector_type(4))) float f32x4;
typedef __attribute__((ext_vector_type(8))) short short8;

#define NBATCH 16
#define NPIX   16384      // H*W
#define NPB    1048576    // per-batch flat elems (C*H*W = 1024*1024)

__device__ __forceinline__ ushort f2bf(float f) {
  u32 b = __builtin_bit_cast(u32, f);
  return (ushort)((b + 0x7FFFu + ((b >> 16) & 1u)) >> 16);
}
__device__ __forceinline__ float bf2f(ushort h) {
  return __builtin_bit_cast(float, (u32)h << 16);
}

// ---------------- Kernel 0: pack weights -------------------------------------
// wp[cb][o][j] = W[o][cb*4+j], o in [0,80): 0..7=q, 8..15=k, 16..79=v.
__global__ void prep_w(const float* __restrict__ Wq, const float* __restrict__ bq,
                       const float* __restrict__ Wk, const float* __restrict__ bk,
                       const float* __restrict__ Wv, const float* __restrict__ bv,
                       float* __restrict__ wp, float* __restrict__ bpk)
{
  int gid = blockIdx.x * 256 + threadIdx.x;
  if (gid < 5120) {
    int cb = gid / 320;
    int r = gid - cb * 320;
    int o = r >> 2, j = r & 3;
    int c = cb * 4 + j;
    float v = (o < 8) ? Wq[o * 64 + c]
            : (o < 16) ? Wk[(o - 8) * 64 + c]
                       : Wv[(o - 16) * 64 + c];
    wp[gid] = v;
  } else if (gid < 5200) {
    int o = gid - 5120;
    bpk[o] = (o < 8) ? bq[o] : (o < 16 ? bk[o - 8] : bv[o - 16]);
  }
}

// ---------------- Kernel 1: projections, LDS-staged x tile -------------------
// Block = 320 threads (5 waves), one 128-pixel tile. x[64][128] staged in LDS
// once (each x element fetched from HBM exactly once chip-wide). Wave w =
// output group w: w==0 -> q+k (split-bf16), w==1..4 -> 16 V channels. Lane
// owns 2 adjacent pixels (acc[16][2]). Weight reads via readfirstlane'd index
// -> s_load (scalar pipe), V stores pack 2 pixels per u32 (coalesced).
__global__ __launch_bounds__(320) void proj4(
    const float* __restrict__ x, const float* __restrict__ wp,
    const float* __restrict__ bpk,
    ushort* __restrict__ Qt2, ushort* __restrict__ Kt2,
    ushort* __restrict__ Vnat)
{
  __shared__ float xs[64][128];
  int t = threadIdx.x;
  int tile = blockIdx.x;           // 2048 = 16 batches x 128 tiles
  int b = tile >> 7;
  int p0 = (tile & 127) << 7;
  const float* xb = x + (size_t)b * NPB;

  for (int i = t; i < 8192; i += 320) {
    int ch = i >> 7, pix = i & 127;
    xs[ch][pix] = xb[(size_t)ch * NPIX + p0 + pix];
  }
  __syncthreads();

  int w = t >> 6, j = t & 63;
  int ob = __builtin_amdgcn_readfirstlane(w * 16);

  float acc[16][2];
  #pragma unroll
  for (int o = 0; o < 16; ++o) { float bb = bpk[ob + o]; acc[o][0] = bb; acc[o][1] = bb; }

  const f32x4* wp4 = (const f32x4*)wp;
  for (int cb = 0; cb < 16; ++cb) {
    float2 xv0 = *(const float2*)&xs[cb * 4 + 0][j * 2];
    float2 xv1 = *(const float2*)&xs[cb * 4 + 1][j * 2];
    float2 xv2 = *(const float2*)&xs[cb * 4 + 2][j * 2];
    float2 xv3 = *(const float2*)&xs[cb * 4 + 3][j * 2];
    #pragma unroll
    for (int o = 0; o < 16; ++o) {
      f32x4 wv = wp4[cb * 80 + ob + o];
      acc[o][0] += wv[0] * xv0.x + wv[1] * xv1.x + wv[2] * xv2.x + wv[3] * xv3.x;
      acc[o][1] += wv[0] * xv0.y + wv[1] * xv1.y + wv[2] * xv2.y + wv[3] * xv3.y;
    }
  }

  if (w == 0) {
    // Q/K split bf16: Q = [qh][ql][qh], K = [kh][kh][kl] so that
    // dot = qh*kh + ql*kh + qh*kl (drops only ~2e-4 ql*kl term).
    #pragma unroll
    for (int i = 0; i < 2; ++i) {
      int p = p0 + j * 2 + i;
      int l = p & 1023, tc = p >> 10;
      union { ushort s[8]; uint4 q; } qh, ql, kh, kl;
      #pragma unroll
      for (int o = 0; o < 8; ++o) {
        float qv = acc[o][i];
        ushort h = f2bf(qv);
        qh.s[o] = h; ql.s[o] = f2bf(qv - bf2f(h));
        float kv = acc[8 + o][i];
        h = f2bf(kv);
        kh.s[o] = h; kl.s[o] = f2bf(kv - bf2f(h));
      }
      ushort* qrow = Qt2 + ((size_t)b * 1024 + l) * 384 + tc * 8;
      *(uint4*)qrow         = qh.q;
      *(uint4*)(qrow + 128) = ql.q;
      *(uint4*)(qrow + 256) = qh.q;
      ushort* krow = Kt2 + ((size_t)b * 1024 + l) * 384 + tc * 8;
      *(uint4*)krow         = kh.q;
      *(uint4*)(krow + 128) = kh.q;
      *(uint4*)(krow + 256) = kl.q;
    }
  } else {
    int cbase = ob - 16;
    ushort* vb = Vnat + (size_t)b * NPB + (size_t)cbase * NPIX + p0 + j * 2;
    #pragma unroll
    for (int c = 0; c < 16; ++c) {
      u32 pk = (u32)f2bf(acc[c][0]) | ((u32)f2bf(acc[c][1]) << 16);
      *(u32*)(vb + (size_t)c * NPIX) = pk;
    }
  }
}

// ---------------- Kernel 2: V transpose --------------------------------------
// Vt[a][p'] = Vnat_flat[p'*1024 + a]  (verified correct in round 1)
__global__ __launch_bounds__(256) void transpose_v(
    const ushort* __restrict__ Vnat, ushort* __restrict__ Vt)
{
  __shared__ ushort tile[64][80];
  int b = blockIdx.y;
  int p0 = (blockIdx.x >> 4) << 6;
  int c0 = (blockIdx.x & 15) << 6;
  int t = threadIdx.x;
  int pr = t >> 2, ch = t & 3;
  int p = p0 + pr;
  const ushort* src = Vnat + (size_t)b * NPB + (size_t)(p >> 4) * NPIX +
                      (size_t)(p & 15) * 1024 + c0 + ch * 16;
  uint4 v0 = ((const uint4*)src)[0];
  uint4 v1 = ((const uint4*)src)[1];
  *(uint4*)&tile[pr][ch * 16] = v0;
  *(uint4*)&tile[pr][ch * 16 + 8] = v1;
  __syncthreads();
  int cl = t >> 2, pch = t & 3;
  union { ushort s[16]; uint4 q[2]; } outv;
  #pragma unroll
  for (int j = 0; j < 16; ++j) outv.s[j] = tile[pch * 16 + j][cl];
  ushort* dst = Vt + (size_t)b * NPB + (size_t)(c0 + cl) * 1024 + p0 + pch * 16;
  ((uint4*)dst)[0] = outv.q[0];
  ((uint4*)dst)[1] = outv.q[1];
}

// ---------------- Kernels 3/5: NT bf16 MFMA GEMM -----------------------------
// C[i][j] = sum_k A[i][k]*B[j][k]; per-batch 1024x1024, tile 128x128, BK=64.
// 4 waves (2x2), each 64x64 via 4x4 frags of 16x16x32. XOR-swizzled LDS.
template<int KTOT, bool ADDX>
__global__ __launch_bounds__(256) void gemm_nt(
    const ushort* __restrict__ A, int lda,
    const ushort* __restrict__ B, int ldb,
    float* __restrict__ C, const float* __restrict__ X)
{
  __shared__ ushort Asm[128 * 64];
  __shared__ ushort Bsm[128 * 64];
  int t = threadIdx.x;
  int bz = blockIdx.z;
  int m0 = blockIdx.y << 7, n0 = blockIdx.x << 7;
  const ushort* Ab = A + (size_t)bz * 1024 * lda;
  const ushort* Bb = B + (size_t)bz * 1024 * ldb;
  int row = t >> 1, half = t & 1;
  int swz = row & 7;
  int wid = t >> 6, lane = t & 63;
  int wm = wid >> 1, wn = wid & 1;

  f32x4 acc[4][4] = {};
  uint4* as4 = (uint4*)Asm;
  uint4* bs4 = (uint4*)Bsm;
  const uint4* agrow = (const uint4*)(Ab + (size_t)(m0 + row) * lda) + half * 4;
  const uint4* bgrow = (const uint4*)(Bb + (size_t)(n0 + row) * ldb) + half * 4;

  for (int k0 = 0; k0 < KTOT; k0 += 64) {
    uint4 a0 = agrow[0], a1 = agrow[1], a2 = agrow[2], a3 = agrow[3];
    uint4 b0 = bgrow[0], b1 = bgrow[1], b2 = bgrow[2], b3 = bgrow[3];
    agrow += 8; bgrow += 8;
    __syncthreads();
    int sb = row * 8, c0i = half * 4;
    as4[sb + ((c0i + 0) ^ swz)] = a0;
    as4[sb + ((c0i + 1) ^ swz)] = a1;
    as4[sb + ((c0i + 2) ^ swz)] = a2;
    as4[sb + ((c0i + 3) ^ swz)] = a3;
    bs4[sb + ((c0i + 0) ^ swz)] = b0;
    bs4[sb + ((c0i + 1) ^ swz)] = b1;
    bs4[sb + ((c0i + 2) ^ swz)] = b2;
    bs4[sb + ((c0i + 3) ^ swz)] = b3;
    __syncthreads();
    #pragma unroll
    for (int kk = 0; kk < 2; ++kk) {
      short8 af[4], bfr[4];
      #pragma unroll
      for (int mi = 0; mi < 4; ++mi) {
        int r = (wm << 6) + (mi << 4) + (lane & 15);
        af[mi] = __builtin_bit_cast(short8,
            ((const uint4*)Asm)[r * 8 + ((kk * 4 + (lane >> 4)) ^ (r & 7))]);
      }
      #pragma unroll
      for (int ni = 0; ni < 4; ++ni) {
        int r = (wn << 6) + (ni << 4) + (lane & 15);
        bfr[ni] = __builtin_bit_cast(short8,
            ((const uint4*)Bsm)[r * 8 + ((kk * 4 + (lane >> 4)) ^ (r & 7))]);
      }
      #pragma unroll
      for (int mi = 0; mi < 4; ++mi)
        #pragma unroll
        for (int ni = 0; ni < 4; ++ni)
          acc[mi][ni] = __builtin_amdgcn_mfma_f32_16x16x32_bf16(
              af[mi], bfr[ni], acc[mi][ni], 0, 0, 0);
    }
  }

  #pragma unroll
  for (int mi = 0; mi < 4; ++mi) {
    int rbase = m0 + (wm << 6) + (mi << 4) + ((lane >> 4) << 2);
    #pragma unroll
    for (int ni = 0; ni < 4; ++ni) {
      int col = n0 + (wn << 6) + (ni << 4) + (lane & 15);
      f32x4 v = acc[mi][ni];
      #pragma unroll
      for (int r = 0; r < 4; ++r) {
        size_t idx = ((size_t)bz * 1024 + rbase + r) * 1024 + col;
        if (ADDX) C[idx] = v[r] + X[idx];
        else      C[idx] = v[r];
      }
    }
  }
}

// ---------------- Kernel 4: row softmax, P bf16 in place ---------------------
__global__ __launch_bounds__(256) void softmax_rows(float* __restrict__ S)
{
  size_t rowi = blockIdx.x;
  float* srow = S + rowi * 1024;
  int t = threadIdx.x;
  float4 v = ((const float4*)srow)[t];
  float m = fmaxf(fmaxf(v.x, v.y), fmaxf(v.z, v.w));
  #pragma unroll
  for (int off = 32; off > 0; off >>= 1) m = fmaxf(m, __shfl_xor(m, off));
  __shared__ float red[8];
  int wid = t >> 6, lane = t & 63;
  if (lane == 0) red[wid] = m;
  __syncthreads();
  m = fmaxf(fmaxf(red[0], red[1]), fmaxf(red[2], red[3]));
  float e0 = __expf(v.x - m), e1 = __expf(v.y - m);
  float e2 = __expf(v.z - m), e3 = __expf(v.w - m);
  float s = e0 + e1 + e2 + e3;
  #pragma unroll
  for (int off = 32; off > 0; off >>= 1) s += __shfl_xor(s, off);
  if (lane == 0) red[4 + wid] = s;
  __syncthreads();
  s = red[4] + red[5] + red[6] + red[7];
  float inv = 1.0f / s;
  union { ushort h[4]; uint2 q; } pk;
  pk.h[0] = f2bf(e0 * inv); pk.h[1] = f2bf(e1 * inv);
  pk.h[2] = f2bf(e2 * inv); pk.h[3] = f2bf(e3 * inv);
  ((uint2*)srow)[t] = pk.q;
}

// ---------------- Launch -----------------------------------------------------
extern "C" void kernel_launch(void* const* d_in, const int* in_sizes, int n_in,
                              void* d_out, int out_size, void* d_ws, size_t ws_size,
                              hipStream_t stream) {
  const float* x  = (const float*)d_in[0];
  const float* Wq = (const float*)d_in[1];
  const float* bq = (const float*)d_in[2];
  const float* Wk = (const float*)d_in[3];
  const float* bk = (const float*)d_in[4];
  const float* Wv = (const float*)d_in[5];
  const float* bv = (const float*)d_in[6];
  float* out = (float*)d_out;

  char* wsb = (char*)d_ws;
  ushort* Qt2 = (ushort*)wsb;                          // 12,582,912 B
  ushort* Kt2 = (ushort*)(wsb + 12582912);             // 12,582,912 B
  ushort* Vt  = (ushort*)(wsb + 25165824);             // 33,554,432 B
  float*  S   = (float*)(wsb + 58720256);              // 67,108,864 B (P in place)
  ushort* Vnat = (ushort*)S;                           // first 32MB of S (dead before gemm1)
  float*  wp  = (float*)(wsb + 92274688);              // after Vnat, still inside S
  float*  bpk = wp + 5120;

  prep_w<<<21, 256, 0, stream>>>(Wq, bq, Wk, bk, Wv, bv, wp, bpk);
  proj4<<<2048, 320, 0, stream>>>(x, wp, bpk, Qt2, Kt2, Vnat);
  transpose_v<<<dim3(256, 16), 256, 0, stream>>>(Vnat, Vt);
  gemm_nt<384, false><<<dim3(8, 8, 16), 256, 0, stream>>>(Qt2, 384, Kt2, 384, S, nullptr);
  softmax_rows<<<16384, 256, 0, stream>>>(S);
  gemm_nt<1024, true><<<dim3(8, 8, 16), 256, 0, stream>>>((const ushort*)S, 2048, Vt, 1024, out, x);
}

// Round 6
// 176.865 us; speedup vs baseline: 1.4930x; 1.0420x over previous
//
#include <hip/hip_runtime.h>
#include <stdint.h>

typedef uint32_t u32;
typedef __attribute__((ext_vector_type(4))) float f32x4;
typedef __attribute__((ext_vector_type(8))) short short8;

#define NBATCH 16
#define NPIX   16384      // H*W
#define NPB    1048576    // per-batch flat elems (C*H*W = 1024*1024)

__device__ __forceinline__ ushort f2bf(float f) {
  u32 b = __builtin_bit_cast(u32, f);
  return (ushort)((b + 0x7FFFu + ((b >> 16) & 1u)) >> 16);
}
__device__ __forceinline__ float bf2f(ushort h) {
  return __builtin_bit_cast(float, (u32)h << 16);
}

// async global->LDS, 16B per lane. LDS dest must be wave-uniform base;
// HW scatters lane i at base + i*16.
__device__ __forceinline__ void gload16(const ushort* g, ushort* l) {
  __builtin_amdgcn_global_load_lds(
      (const __attribute__((address_space(1))) u32*)(const void*)g,
      (__attribute__((address_space(3))) u32*)(void*)l,
      16, 0, 0);
}

// ---------------- Kernel 0: pack weights -------------------------------------
// wp[cb][o][j] = W[o][cb*4+j], o in [0,80): 0..7=q, 8..15=k, 16..79=v.
__global__ void prep_w(const float* __restrict__ Wq, const float* __restrict__ bq,
                       const float* __restrict__ Wk, const float* __restrict__ bk,
                       const float* __restrict__ Wv, const float* __restrict__ bv,
                       float* __restrict__ wp, float* __restrict__ bpk)
{
  int gid = blockIdx.x * 256 + threadIdx.x;
  if (gid < 5120) {
    int cb = gid / 320;
    int r = gid - cb * 320;
    int o = r >> 2, j = r & 3;
    int c = cb * 4 + j;
    float v = (o < 8) ? Wq[o * 64 + c]
            : (o < 16) ? Wk[(o - 8) * 64 + c]
                       : Wv[(o - 16) * 64 + c];
    wp[gid] = v;
  } else if (gid < 5200) {
    int o = gid - 5120;
    bpk[o] = (o < 8) ? bq[o] : (o < 16 ? bk[o - 8] : bv[o - 16]);
  }
}

// ---------------- Kernel 1: projections, LDS-staged x tile -------------------
// Block = 320 threads (5 waves), one 128-pixel tile. x[64][128] staged in LDS
// once (each x element fetched from HBM exactly once chip-wide). Wave w =
// output group w: w==0 -> q+k (split-bf16), w==1..4 -> 16 V channels.
__global__ __launch_bounds__(320) void proj4(
    const float* __restrict__ x, const float* __restrict__ wp,
    const float* __restrict__ bpk,
    ushort* __restrict__ Qt2, ushort* __restrict__ Kt2,
    ushort* __restrict__ Vnat)
{
  __shared__ float xs[64][128];
  int t = threadIdx.x;
  int tile = blockIdx.x;           // 2048 = 16 batches x 128 tiles
  int b = tile >> 7;
  int p0 = (tile & 127) << 7;
  const float* xb = x + (size_t)b * NPB;

  for (int i = t; i < 8192; i += 320) {
    int ch = i >> 7, pix = i & 127;
    xs[ch][pix] = xb[(size_t)ch * NPIX + p0 + pix];
  }
  __syncthreads();

  int w = t >> 6, j = t & 63;
  int ob = __builtin_amdgcn_readfirstlane(w * 16);

  float acc[16][2];
  #pragma unroll
  for (int o = 0; o < 16; ++o) { float bb = bpk[ob + o]; acc[o][0] = bb; acc[o][1] = bb; }

  const f32x4* wp4 = (const f32x4*)wp;
  for (int cb = 0; cb < 16; ++cb) {
    float2 xv0 = *(const float2*)&xs[cb * 4 + 0][j * 2];
    float2 xv1 = *(const float2*)&xs[cb * 4 + 1][j * 2];
    float2 xv2 = *(const float2*)&xs[cb * 4 + 2][j * 2];
    float2 xv3 = *(const float2*)&xs[cb * 4 + 3][j * 2];
    #pragma unroll
    for (int o = 0; o < 16; ++o) {
      f32x4 wv = wp4[cb * 80 + ob + o];
      acc[o][0] += wv[0] * xv0.x + wv[1] * xv1.x + wv[2] * xv2.x + wv[3] * xv3.x;
      acc[o][1] += wv[0] * xv0.y + wv[1] * xv1.y + wv[2] * xv2.y + wv[3] * xv3.y;
    }
  }

  if (w == 0) {
    // Q/K split bf16: Q = [qh][ql][qh], K = [kh][kh][kl] so that
    // dot = qh*kh + ql*kh + qh*kl (drops only ~2e-4 ql*kl term).
    #pragma unroll
    for (int i = 0; i < 2; ++i) {
      int p = p0 + j * 2 + i;
      int l = p & 1023, tc = p >> 10;
      union { ushort s[8]; uint4 q; } qh, ql, kh, kl;
      #pragma unroll
      for (int o = 0; o < 8; ++o) {
        float qv = acc[o][i];
        ushort h = f2bf(qv);
        qh.s[o] = h; ql.s[o] = f2bf(qv - bf2f(h));
        float kv = acc[8 + o][i];
        h = f2bf(kv);
        kh.s[o] = h; kl.s[o] = f2bf(kv - bf2f(h));
      }
      ushort* qrow = Qt2 + ((size_t)b * 1024 + l) * 384 + tc * 8;
      *(uint4*)qrow         = qh.q;
      *(uint4*)(qrow + 128) = ql.q;
      *(uint4*)(qrow + 256) = qh.q;
      ushort* krow = Kt2 + ((size_t)b * 1024 + l) * 384 + tc * 8;
      *(uint4*)krow         = kh.q;
      *(uint4*)(krow + 128) = kh.q;
      *(uint4*)(krow + 256) = kl.q;
    }
  } else {
    int cbase = ob - 16;
    ushort* vb = Vnat + (size_t)b * NPB + (size_t)cbase * NPIX + p0 + j * 2;
    #pragma unroll
    for (int c = 0; c < 16; ++c) {
      u32 pk = (u32)f2bf(acc[c][0]) | ((u32)f2bf(acc[c][1]) << 16);
      *(u32*)(vb + (size_t)c * NPIX) = pk;
    }
  }
}

// ---------------- Kernel 2: V transpose --------------------------------------
// Vt[a][p'] = Vnat_flat[p'*1024 + a]
__global__ __launch_bounds__(256) void transpose_v(
    const ushort* __restrict__ Vnat, ushort* __restrict__ Vt)
{
  __shared__ ushort tile[64][80];
  int b = blockIdx.y;
  int p0 = (blockIdx.x >> 4) << 6;
  int c0 = (blockIdx.x & 15) << 6;
  int t = threadIdx.x;
  int pr = t >> 2, ch = t & 3;
  int p = p0 + pr;
  const ushort* src = Vnat + (size_t)b * NPB + (size_t)(p >> 4) * NPIX +
                      (size_t)(p & 15) * 1024 + c0 + ch * 16;
  uint4 v0 = ((const uint4*)src)[0];
  uint4 v1 = ((const uint4*)src)[1];
  *(uint4*)&tile[pr][ch * 16] = v0;
  *(uint4*)&tile[pr][ch * 16 + 8] = v1;
  __syncthreads();
  int cl = t >> 2, pch = t & 3;
  union { ushort s[16]; uint4 q[2]; } outv;
  #pragma unroll
  for (int j = 0; j < 16; ++j) outv.s[j] = tile[pch * 16 + j][cl];
  ushort* dst = Vt + (size_t)b * NPB + (size_t)(c0 + cl) * 1024 + p0 + pch * 16;
  ((uint4*)dst)[0] = outv.q[0];
  ((uint4*)dst)[1] = outv.q[1];
}

// ---------------- Kernels 3/5: NT bf16 MFMA GEMM (m97 structure) -------------
// C[i][j] = sum_k A[i][k]*B[j][k]; per-batch 1024x1024, tile 128x128, BK=64.
// global_load_lds width-16 staging into LINEAR LDS (bank conflicts hidden at
// 2-phase), 4 waves (2x2), each 64x64 via 4x4 frags of 16x16x32.
// 1D grid 1024 blocks, XCD-chunked: each XCD owns 2 contiguous batches so
// P/Vt panels (2+2 MB/batch) stay resident in its 4 MB L2.
template<int KTOT, bool ADDX>
__global__ __launch_bounds__(256) void gemm_nt(
    const ushort* __restrict__ A, int lda,
    const ushort* __restrict__ B, int ldb,
    float* __restrict__ C, const float* __restrict__ X)
{
  __shared__ ushort Asm[128 * 64];
  __shared__ ushort Bsm[128 * 64];
  int t = threadIdx.x;

  // bijective XCD-chunk remap (1024 blocks, 8 XCDs, 128 each = 2 batches)
  int g = blockIdx.x;
  int lin = (g & 7) * 128 + (g >> 3);
  int bz = lin >> 6;
  int by = (lin >> 3) & 7;
  int bx = lin & 7;
  int m0 = by << 7, n0 = bx << 7;

  const ushort* Ab = A + (size_t)bz * 1024 * lda;
  const ushort* Bb = B + (size_t)bz * 1024 * ldb;
  int wid = t >> 6, lane = t & 63;
  int wm = wid >> 1, wn = wid & 1;

  // staging addresses: round i loads rows [i*32, i*32+32), thread t covers
  // row i*32 + (t>>3), elems [(t&7)*8, +8) -> LDS flat byte i*4096 + t*16.
  const ushort* pa = Ab + (size_t)(m0 + (t >> 3)) * lda + (t & 7) * 8;
  const ushort* pb = Bb + (size_t)(n0 + (t >> 3)) * ldb + (t & 7) * 8;
  ushort* la0 = Asm + (size_t)(t >> 6) * 512;   // wave base, elems (1024 B)
  ushort* lb0 = Bsm + (size_t)(t >> 6) * 512;

  f32x4 acc[4][4] = {};

  for (int k0 = 0; k0 < KTOT; k0 += 64) {
    __syncthreads();                 // previous compute done before overwrite
    #pragma unroll
    for (int i = 0; i < 4; ++i)
      gload16(pa + (size_t)i * 32 * lda + k0, la0 + i * 2048);
    #pragma unroll
    for (int i = 0; i < 4; ++i)
      gload16(pb + (size_t)i * 32 * ldb + k0, lb0 + i * 2048);
    __syncthreads();                 // drains vmcnt (lds) + barrier
    #pragma unroll
    for (int kk = 0; kk < 2; ++kk) {
      short8 af[4], bfr[4];
      #pragma unroll
      for (int mi = 0; mi < 4; ++mi) {
        int r = (wm << 6) + (mi << 4) + (lane & 15);
        af[mi] = __builtin_bit_cast(short8,
            ((const uint4*)Asm)[r * 8 + kk * 4 + (lane >> 4)]);
      }
      #pragma unroll
      for (int ni = 0; ni < 4; ++ni) {
        int r = (wn << 6) + (ni << 4) + (lane & 15);
        bfr[ni] = __builtin_bit_cast(short8,
            ((const uint4*)Bsm)[r * 8 + kk * 4 + (lane >> 4)]);
      }
      #pragma unroll
      for (int mi = 0; mi < 4; ++mi)
        #pragma unroll
        for (int ni = 0; ni < 4; ++ni)
          acc[mi][ni] = __builtin_amdgcn_mfma_f32_16x16x32_bf16(
              af[mi], bfr[ni], acc[mi][ni], 0, 0, 0);
    }
  }

  #pragma unroll
  for (int mi = 0; mi < 4; ++mi) {
    int rbase = m0 + (wm << 6) + (mi << 4) + ((lane >> 4) << 2);
    #pragma unroll
    for (int ni = 0; ni < 4; ++ni) {
      int col = n0 + (wn << 6) + (ni << 4) + (lane & 15);
      f32x4 v = acc[mi][ni];
      #pragma unroll
      for (int r = 0; r < 4; ++r) {
        size_t idx = ((size_t)bz * 1024 + rbase + r) * 1024 + col;
        if (ADDX) C[idx] = v[r] + X[idx];
        else      C[idx] = v[r];
      }
    }
  }
}

// ---------------- Kernel 4: row softmax, P bf16 in place ---------------------
__global__ __launch_bounds__(256) void softmax_rows(float* __restrict__ S)
{
  size_t rowi = blockIdx.x;
  float* srow = S + rowi * 1024;
  int t = threadIdx.x;
  float4 v = ((const float4*)srow)[t];
  float m = fmaxf(fmaxf(v.x, v.y), fmaxf(v.z, v.w));
  #pragma unroll
  for (int off = 32; off > 0; off >>= 1) m = fmaxf(m, __shfl_xor(m, off));
  __shared__ float red[8];
  int wid = t >> 6, lane = t & 63;
  if (lane == 0) red[wid] = m;
  __syncthreads();
  m = fmaxf(fmaxf(red[0], red[1]), fmaxf(red[2], red[3]));
  float e0 = __expf(v.x - m), e1 = __expf(v.y - m);
  float e2 = __expf(v.z - m), e3 = __expf(v.w - m);
  float s = e0 + e1 + e2 + e3;
  #pragma unroll
  for (int off = 32; off > 0; off >>= 1) s += __shfl_xor(s, off);
  if (lane == 0) red[4 + wid] = s;
  __syncthreads();
  s = red[4] + red[5] + red[6] + red[7];
  float inv = 1.0f / s;
  union { ushort h[4]; uint2 q; } pk;
  pk.h[0] = f2bf(e0 * inv); pk.h[1] = f2bf(e1 * inv);
  pk.h[2] = f2bf(e2 * inv); pk.h[3] = f2bf(e3 * inv);
  ((uint2*)srow)[t] = pk.q;
}

// ---------------- Launch -----------------------------------------------------
extern "C" void kernel_launch(void* const* d_in, const int* in_sizes, int n_in,
                              void* d_out, int out_size, void* d_ws, size_t ws_size,
                              hipStream_t stream) {
  const float* x  = (const float*)d_in[0];
  const float* Wq = (const float*)d_in[1];
  const float* bq = (const float*)d_in[2];
  const float* Wk = (const float*)d_in[3];
  const float* bk = (const float*)d_in[4];
  const float* Wv = (const float*)d_in[5];
  const float* bv = (const float*)d_in[6];
  float* out = (float*)d_out;

  char* wsb = (char*)d_ws;
  ushort* Qt2 = (ushort*)wsb;                          // 12,582,912 B
  ushort* Kt2 = (ushort*)(wsb + 12582912);             // 12,582,912 B
  ushort* Vt  = (ushort*)(wsb + 25165824);             // 33,554,432 B
  float*  S   = (float*)(wsb + 58720256);              // 67,108,864 B (P in place)
  ushort* Vnat = (ushort*)S;                           // first 32MB of S (dead before gemm1)
  float*  wp  = (float*)(wsb + 92274688);              // after Vnat, still inside S
  float*  bpk = wp + 5120;

  prep_w<<<21, 256, 0, stream>>>(Wq, bq, Wk, bk, Wv, bv, wp, bpk);
  proj4<<<2048, 320, 0, stream>>>(x, wp, bpk, Qt2, Kt2, Vnat);
  transpose_v<<<dim3(256, 16), 256, 0, stream>>>(Vnat, Vt);
  gemm_nt<384, false><<<1024, 256, 0, stream>>>(Qt2, 384, Kt2, 384, S, nullptr);
  softmax_rows<<<16384, 256, 0, stream>>>(S);
  gemm_nt<1024, true><<<1024, 256, 0, stream>>>((const ushort*)S, 2048, Vt, 1024, out, x);
}

// Round 7
// 163.299 us; speedup vs baseline: 1.6171x; 1.0831x over previous
//
#include <hip/hip_runtime.h>
#include <stdint.h>

typedef uint32_t u32;
typedef __attribute__((ext_vector_type(4))) float f32x4;
typedef __attribute__((ext_vector_type(8))) short short8;

#define NBATCH 16
#define NPIX   16384      // H*W
#define NPB    1048576    // per-batch flat elems (C*H*W = 1024*1024)

__device__ __forceinline__ ushort f2bf(float f) {
  u32 b = __builtin_bit_cast(u32, f);
  return (ushort)((b + 0x7FFFu + ((b >> 16) & 1u)) >> 16);
}
__device__ __forceinline__ float bf2f(ushort h) {
  return __builtin_bit_cast(float, (u32)h << 16);
}

// async global->LDS, 16B per lane. LDS dest must be wave-uniform base;
// HW scatters lane i at base + i*16.
__device__ __forceinline__ void gload16(const ushort* g, ushort* l) {
  __builtin_amdgcn_global_load_lds(
      (const __attribute__((address_space(1))) u32*)(const void*)g,
      (__attribute__((address_space(3))) u32*)(void*)l,
      16, 0, 0);
}

// ---------------- Kernel 0: pack weights -------------------------------------
// wp[cb][o][j] = W[o][cb*4+j], o in [0,80): 0..7=q, 8..15=k, 16..79=v.
__global__ void prep_w(const float* __restrict__ Wq, const float* __restrict__ bq,
                       const float* __restrict__ Wk, const float* __restrict__ bk,
                       const float* __restrict__ Wv, const float* __restrict__ bv,
                       float* __restrict__ wp, float* __restrict__ bpk)
{
  int gid = blockIdx.x * 256 + threadIdx.x;
  if (gid < 5120) {
    int cb = gid / 320;
    int r = gid - cb * 320;
    int o = r >> 2, j = r & 3;
    int c = cb * 4 + j;
    float v = (o < 8) ? Wq[o * 64 + c]
            : (o < 16) ? Wk[(o - 8) * 64 + c]
                       : Wv[(o - 16) * 64 + c];
    wp[gid] = v;
  } else if (gid < 5200) {
    int o = gid - 5120;
    bpk[o] = (o < 8) ? bq[o] : (o < 16 ? bk[o - 8] : bv[o - 16]);
  }
}

// ---------------- Kernel 1: projections, LDS-staged x tile -------------------
// Block = 320 threads (5 waves), one 128-pixel tile. x[64][128] staged in LDS
// once (each x element fetched from HBM exactly once chip-wide). Wave w =
// output group w: w==0 -> q+k (split-bf16), w==1..4 -> 16 V channels.
__global__ __launch_bounds__(320) void proj4(
    const float* __restrict__ x, const float* __restrict__ wp,
    const float* __restrict__ bpk,
    ushort* __restrict__ Qt2, ushort* __restrict__ Kt2,
    ushort* __restrict__ Vnat)
{
  __shared__ float xs[64][128];
  int t = threadIdx.x;
  int tile = blockIdx.x;           // 2048 = 16 batches x 128 tiles
  int b = tile >> 7;
  int p0 = (tile & 127) << 7;
  const float* xb = x + (size_t)b * NPB;

  for (int i = t; i < 8192; i += 320) {
    int ch = i >> 7, pix = i & 127;
    xs[ch][pix] = xb[(size_t)ch * NPIX + p0 + pix];
  }
  __syncthreads();

  int w = t >> 6, j = t & 63;
  int ob = __builtin_amdgcn_readfirstlane(w * 16);

  float acc[16][2];
  #pragma unroll
  for (int o = 0; o < 16; ++o) { float bb = bpk[ob + o]; acc[o][0] = bb; acc[o][1] = bb; }

  const f32x4* wp4 = (const f32x4*)wp;
  for (int cb = 0; cb < 16; ++cb) {
    float2 xv0 = *(const float2*)&xs[cb * 4 + 0][j * 2];
    float2 xv1 = *(const float2*)&xs[cb * 4 + 1][j * 2];
    float2 xv2 = *(const float2*)&xs[cb * 4 + 2][j * 2];
    float2 xv3 = *(const float2*)&xs[cb * 4 + 3][j * 2];
    #pragma unroll
    for (int o = 0; o < 16; ++o) {
      f32x4 wv = wp4[cb * 80 + ob + o];
      acc[o][0] += wv[0] * xv0.x + wv[1] * xv1.x + wv[2] * xv2.x + wv[3] * xv3.x;
      acc[o][1] += wv[0] * xv0.y + wv[1] * xv1.y + wv[2] * xv2.y + wv[3] * xv3.y;
    }
  }

  if (w == 0) {
    // Q/K split bf16: Q = [qh][ql][qh], K = [kh][kh][kl] so that
    // dot = qh*kh + ql*kh + qh*kl (drops only ~2e-4 ql*kl term).
    #pragma unroll
    for (int i = 0; i < 2; ++i) {
      int p = p0 + j * 2 + i;
      int l = p & 1023, tc = p >> 10;
      union { ushort s[8]; uint4 q; } qh, ql, kh, kl;
      #pragma unroll
      for (int o = 0; o < 8; ++o) {
        float qv = acc[o][i];
        ushort h = f2bf(qv);
        qh.s[o] = h; ql.s[o] = f2bf(qv - bf2f(h));
        float kv = acc[8 + o][i];
        h = f2bf(kv);
        kh.s[o] = h; kl.s[o] = f2bf(kv - bf2f(h));
      }
      ushort* qrow = Qt2 + ((size_t)b * 1024 + l) * 384 + tc * 8;
      *(uint4*)qrow         = qh.q;
      *(uint4*)(qrow + 128) = ql.q;
      *(uint4*)(qrow + 256) = qh.q;
      ushort* krow = Kt2 + ((size_t)b * 1024 + l) * 384 + tc * 8;
      *(uint4*)krow         = kh.q;
      *(uint4*)(krow + 128) = kh.q;
      *(uint4*)(krow + 256) = kl.q;
    }
  } else {
    int cbase = ob - 16;
    ushort* vb = Vnat + (size_t)b * NPB + (size_t)cbase * NPIX + p0 + j * 2;
    #pragma unroll
    for (int c = 0; c < 16; ++c) {
      u32 pk = (u32)f2bf(acc[c][0]) | ((u32)f2bf(acc[c][1]) << 16);
      *(u32*)(vb + (size_t)c * NPIX) = pk;
    }
  }
}

// ---------------- Kernel 2: V transpose --------------------------------------
// Vt[a][p'] = Vnat_flat[p'*1024 + a]
__global__ __launch_bounds__(256) void transpose_v(
    const ushort* __restrict__ Vnat, ushort* __restrict__ Vt)
{
  __shared__ ushort tile[64][80];
  int b = blockIdx.y;
  int p0 = (blockIdx.x >> 4) << 6;
  int c0 = (blockIdx.x & 15) << 6;
  int t = threadIdx.x;
  int pr = t >> 2, ch = t & 3;
  int p = p0 + pr;
  const ushort* src = Vnat + (size_t)b * NPB + (size_t)(p >> 4) * NPIX +
                      (size_t)(p & 15) * 1024 + c0 + ch * 16;
  uint4 v0 = ((const uint4*)src)[0];
  uint4 v1 = ((const uint4*)src)[1];
  *(uint4*)&tile[pr][ch * 16] = v0;
  *(uint4*)&tile[pr][ch * 16 + 8] = v1;
  __syncthreads();
  int cl = t >> 2, pch = t & 3;
  union { ushort s[16]; uint4 q[2]; } outv;
  #pragma unroll
  for (int j = 0; j < 16; ++j) outv.s[j] = tile[pch * 16 + j][cl];
  ushort* dst = Vt + (size_t)b * NPB + (size_t)(c0 + cl) * 1024 + p0 + pch * 16;
  ((uint4*)dst)[0] = outv.q[0];
  ((uint4*)dst)[1] = outv.q[1];
}

// ---------------- Kernels 3/5: NT bf16 MFMA GEMM (m97 + src-side swizzle) ----
// C[i][j] = sum_k A[i][k]*B[j][k]; per-batch 1024x1024, tile 128x128, BK=64.
// global_load_lds width-16 staging. Rule #21: LDS dest stays LINEAR; the
// global SOURCE chunk index is XOR-pre-swizzled (chunk' = chunk ^ (row&7)),
// and fragment reads apply the same XOR -> LDS[r][c] holds global[r][c^(r&7)],
// read banks spread 8-ways => 2 lanes/bank (free). Kills the 16-way conflict.
// 1D grid 1024 blocks, XCD-chunked (2 contiguous batches per XCD).
template<int KTOT, bool ADDX>
__global__ __launch_bounds__(256) void gemm_nt(
    const ushort* __restrict__ A, int lda,
    const ushort* __restrict__ B, int ldb,
    float* __restrict__ C, const float* __restrict__ X)
{
  __shared__ ushort Asm[128 * 64];
  __shared__ ushort Bsm[128 * 64];
  int t = threadIdx.x;

  // bijective XCD-chunk remap (1024 blocks, 8 XCDs, 128 each = 2 batches)
  int g = blockIdx.x;
  int lin = (g & 7) * 128 + (g >> 3);
  int bz = lin >> 6;
  int by = (lin >> 3) & 7;
  int bx = lin & 7;
  int m0 = by << 7, n0 = bx << 7;

  const ushort* Ab = A + (size_t)bz * 1024 * lda;
  const ushort* Bb = B + (size_t)bz * 1024 * ldb;
  int wid = t >> 6, lane = t & 63;
  int wm = wid >> 1, wn = wid & 1;

  // staging: thread t covers row (t>>3) (+i*32 per round), global 16B-chunk
  // ((t&7) ^ ((t>>3)&7)) of the 64-elem row segment. Row steps by 32 keep
  // (row&7) invariant, so the swizzled chunk offset is loop-invariant.
  int swc = (t & 7) ^ ((t >> 3) & 7);
  const ushort* pa = Ab + (size_t)(m0 + (t >> 3)) * lda + swc * 8;
  const ushort* pb = Bb + (size_t)(n0 + (t >> 3)) * ldb + swc * 8;
  ushort* la0 = Asm + (size_t)(t >> 6) * 512;   // wave base, elems (1024 B)
  ushort* lb0 = Bsm + (size_t)(t >> 6) * 512;

  f32x4 acc[4][4] = {};

  for (int k0 = 0; k0 < KTOT; k0 += 64) {
    __syncthreads();                 // previous compute done before overwrite
    #pragma unroll
    for (int i = 0; i < 4; ++i)
      gload16(pa + (size_t)i * 32 * lda + k0, la0 + i * 2048);
    #pragma unroll
    for (int i = 0; i < 4; ++i)
      gload16(pb + (size_t)i * 32 * ldb + k0, lb0 + i * 2048);
    __syncthreads();                 // drains vmcnt (lds) + barrier
    #pragma unroll
    for (int kk = 0; kk < 2; ++kk) {
      short8 af[4], bfr[4];
      #pragma unroll
      for (int mi = 0; mi < 4; ++mi) {
        int r = (wm << 6) + (mi << 4) + (lane & 15);
        af[mi] = __builtin_bit_cast(short8,
            ((const uint4*)Asm)[r * 8 + ((kk * 4 + (lane >> 4)) ^ (r & 7))]);
      }
      #pragma unroll
      for (int ni = 0; ni < 4; ++ni) {
        int r = (wn << 6) + (ni << 4) + (lane & 15);
        bfr[ni] = __builtin_bit_cast(short8,
            ((const uint4*)Bsm)[r * 8 + ((kk * 4 + (lane >> 4)) ^ (r & 7))]);
      }
      #pragma unroll
      for (int mi = 0; mi < 4; ++mi)
        #pragma unroll
        for (int ni = 0; ni < 4; ++ni)
          acc[mi][ni] = __builtin_amdgcn_mfma_f32_16x16x32_bf16(
              af[mi], bfr[ni], acc[mi][ni], 0, 0, 0);
    }
  }

  #pragma unroll
  for (int mi = 0; mi < 4; ++mi) {
    int rbase = m0 + (wm << 6) + (mi << 4) + ((lane >> 4) << 2);
    #pragma unroll
    for (int ni = 0; ni < 4; ++ni) {
      int col = n0 + (wn << 6) + (ni << 4) + (lane & 15);
      f32x4 v = acc[mi][ni];
      #pragma unroll
      for (int r = 0; r < 4; ++r) {
        size_t idx = ((size_t)bz * 1024 + rbase + r) * 1024 + col;
        if (ADDX) C[idx] = v[r] + X[idx];
        else      C[idx] = v[r];
      }
    }
  }
}

// ---------------- Kernel 4: row softmax, P bf16 in place ---------------------
__global__ __launch_bounds__(256) void softmax_rows(float* __restrict__ S)
{
  size_t rowi = blockIdx.x;
  float* srow = S + rowi * 1024;
  int t = threadIdx.x;
  float4 v = ((const float4*)srow)[t];
  float m = fmaxf(fmaxf(v.x, v.y), fmaxf(v.z, v.w));
  #pragma unroll
  for (int off = 32; off > 0; off >>= 1) m = fmaxf(m, __shfl_xor(m, off));
  __shared__ float red[8];
  int wid = t >> 6, lane = t & 63;
  if (lane == 0) red[wid] = m;
  __syncthreads();
  m = fmaxf(fmaxf(red[0], red[1]), fmaxf(red[2], red[3]));
  float e0 = __expf(v.x - m), e1 = __expf(v.y - m);
  float e2 = __expf(v.z - m), e3 = __expf(v.w - m);
  float s = e0 + e1 + e2 + e3;
  #pragma unroll
  for (int off = 32; off > 0; off >>= 1) s += __shfl_xor(s, off);
  if (lane == 0) red[4 + wid] = s;
  __syncthreads();
  s = red[4] + red[5] + red[6] + red[7];
  float inv = 1.0f / s;
  union { ushort h[4]; uint2 q; } pk;
  pk.h[0] = f2bf(e0 * inv); pk.h[1] = f2bf(e1 * inv);
  pk.h[2] = f2bf(e2 * inv); pk.h[3] = f2bf(e3 * inv);
  ((uint2*)srow)[t] = pk.q;
}

// ---------------- Launch -----------------------------------------------------
extern "C" void kernel_launch(void* const* d_in, const int* in_sizes, int n_in,
                              void* d_out, int out_size, void* d_ws, size_t ws_size,
                              hipStream_t stream) {
  const float* x  = (const float*)d_in[0];
  const float* Wq = (const float*)d_in[1];
  const float* bq = (const float*)d_in[2];
  const float* Wk = (const float*)d_in[3];
  const float* bk = (const float*)d_in[4];
  const float* Wv = (const float*)d_in[5];
  const float* bv = (const float*)d_in[6];
  float* out = (float*)d_out;

  char* wsb = (char*)d_ws;
  ushort* Qt2 = (ushort*)wsb;                          // 12,582,912 B
  ushort* Kt2 = (ushort*)(wsb + 12582912);             // 12,582,912 B
  ushort* Vt  = (ushort*)(wsb + 25165824);             // 33,554,432 B
  float*  S   = (float*)(wsb + 58720256);              // 67,108,864 B (P in place)
  ushort* Vnat = (ushort*)S;                           // first 32MB of S (dead before gemm1)
  float*  wp  = (float*)(wsb + 92274688);              // after Vnat, still inside S
  float*  bpk = wp + 5120;

  prep_w<<<21, 256, 0, stream>>>(Wq, bq, Wk, bk, Wv, bv, wp, bpk);
  proj4<<<2048, 320, 0, stream>>>(x, wp, bpk, Qt2, Kt2, Vnat);
  transpose_v<<<dim3(256, 16), 256, 0, stream>>>(Vnat, Vt);
  gemm_nt<384, false><<<1024, 256, 0, stream>>>(Qt2, 384, Kt2, 384, S, nullptr);
  softmax_rows<<<16384, 256, 0, stream>>>(S);
  gemm_nt<1024, true><<<1024, 256, 0, stream>>>((const ushort*)S, 2048, Vt, 1024, out, x);
}